// Round 1
// baseline (426.628 us; speedup 1.0000x reference)
//
#include <hip/hip_runtime.h>

typedef unsigned short u16;
typedef __attribute__((ext_vector_type(8))) short bf16x8;   // 8 x bf16 (4 VGPRs)
typedef __attribute__((ext_vector_type(4))) float f32x4;

#define NLEV 5
#define CCH 256
#define KTOT 2304            // 9 taps * 256 ci
#define P_TOT 8525           // sum HW
#define PP_TOT 9165          // sum (H+2)*(W+2)
#define PLS (PP_TOT*64)      // activation plane stride (u16), 4 planes of 64 ci
#define HSTR 11776           // halo LDS plane stride (u16) = 23 slabs * 512

__constant__ int   c_HW[NLEV]     = {6400, 1600, 400, 100, 25};
__constant__ int   c_W[NLEV]      = {80, 40, 20, 10, 5};    // H == W (square)
__constant__ int   c_off[NLEV]    = {0, 6400, 8000, 8400, 8500};
__constant__ int   c_poff[NLEV]   = {0, 6724, 8488, 8972, 9116};
__constant__ int   c_tls[NLEV+1]  = {0, 50, 65, 71, 73, 74};  // 16x8 tile starts
__constant__ int   c_ntx[NLEV]    = {5, 3, 2, 1, 1};          // tiles across
__constant__ float c_stridef[NLEV]= {8.f, 16.f, 32.f, 64.f, 128.f};

__device__ __forceinline__ u16 f2bf(float f){
  union { float f; unsigned u; } v; v.f = f;
  unsigned r = v.u + 0x7fffu + ((v.u >> 16) & 1u);   // RNE
  return (u16)(r >> 16);
}

// async global->LDS: 64 lanes x 16B; HW writes lane i to ldsbase + i*16.
__device__ __forceinline__ void g2l16(const u16* g, u16* l, int lane){
#if defined(__has_builtin)
#if __has_builtin(__builtin_amdgcn_global_load_lds)
  __builtin_amdgcn_global_load_lds(
      (const __attribute__((address_space(1))) unsigned int*)g,
      (__attribute__((address_space(3))) unsigned int*)l, 16, 0, 0);
  return;
#endif
#endif
  *(uint4*)(l + lane*8) = *(const uint4*)g;  // fallback: sync copy
}

// s_waitcnt imm (gfx9: vm[3:0] bits3:0, vm[5:4] bits15:14, exp[6:4], lgkm[11:8])
#define WAIT_VM4    0x0F74   // vmcnt(4)
#define WAIT_VM10   0x0F7A   // vmcnt(10)
#define WAIT_VM0    0x0F70   // vmcnt(0)
#define WAIT_LGKM0  0xC07F   // lgkmcnt(0)
#define WAIT_LGKM10 0xCA7F   // lgkmcnt(10): newest 10 ds_reads may fly

// ---------------------------------------------------------------------------
// Wave-chain halo implicit-GEMM conv 3x3, 2 blocks/CU (LDS 80,000 B).
// BM=128 (blockIdx.y = mtile): each wave owns 32 co; A staged wave-private
// (4 slabs/stage, 8 KB dbuf/wave) with per-wave counted vmcnt waits.
// v2 K-loop: SOFTWARE-PIPELINED FRAGMENTS. Each t is split into two
// 16-MFMA clusters (sub0/sub1 = the two 32-ci halves of the 64-ci stage):
//   top:   lgkm wait (sub0(t) frags prefetched last iter) -> issue sub1(t)
//          reads -> lgkmcnt(10) -> MFMA sub0
//   mid:   lgkmcnt(0) (A/B LDS bufs reusable) -> stageA(t+2) [-> stageH] ->
//          counted vmcnt proving A(t+1) landed -> issue sub0(t+1) reads
//   end:   MFMA sub1
// so every MFMA cluster starts with operands resident; LDS latency hides
// under the other cluster. Prefetch skipped at t=17/26 (t+1 reads a halo
// plane only proven complete by the t=18/27 barrier -> cross-wave race);
// those iterations use the old full-read pattern. vmcnt schedule re-derived
// for issue order (A before H at boundaries): vmcnt(10) at t in {9,10,19}
// and t=18-mid; vmcnt(0) at t=34; vmcnt(4) otherwise. setprio(1) wraps each
// MFMA cluster (waves are role-diverse: wave-private chains, 3 barriers).
// MODE 0: towers, grid (74,2,2); GN stats fused in epilogue.
// MODE 1: heads,  grid (74,1,2): br0 score (m<80), br1 pred+iou (m<5).
// ---------------------------------------------------------------------------
template<int MODE>
__global__ __launch_bounds__(256, 2) void gemm_conv(
    const u16* __restrict__ Xc, const u16* __restrict__ Xb,
    const u16* __restrict__ Wc, const u16* __restrict__ Wb,
    const float* __restrict__ bc, const float* __restrict__ bb,
    float* __restrict__ Yc, float* __restrict__ Yb,
    float* __restrict__ stats,
    const float* __restrict__ predb, const float* __restrict__ ioub,
    const float* __restrict__ scales, float* __restrict__ out)
{
  __shared__ u16 hB[2*HSTR];        // 47104 B: halo plane dbuf (slot = cc&1)
  __shared__ u16 sA[4][2][2048];    // 32768 B: per-wave A dbuf (4 slabs each)
  __shared__ float sstat[16][2];    // 128 B

  const int ptile = blockIdx.x;
  const int mtile = (MODE == 0) ? blockIdx.y : 0;
  const int br = blockIdx.z;
  int lv = 0;
  #pragma unroll
  for (int i = 1; i < NLEV; i++) if (ptile >= c_tls[i]) lv = i;
  const int tidx = ptile - c_tls[lv];
  const int ntx = c_ntx[lv];
  const int ty0 = (tidx / ntx) * 8, tx0 = (tidx - (tidx / ntx) * ntx) * 16;
  const int W = c_W[lv], wrow2 = W + 2;

  const int tid = threadIdx.x, wv = tid >> 6, ln = tid & 63;
  const int quad = ln >> 4, l15 = ln & 15;

  const u16* __restrict__ X  = br ? Xb : Xc;   // planar activations
  const u16* __restrict__ WA = br ? Wb : Wc;   // packed weights

  const int ASTR = (MODE == 0) ? 16384 : 8192; // per-stage A u16s
  const u16* abase = WA +
      (size_t)(((MODE == 0) ? mtile*16 : 0) + wv*4) * 512 + ln*8;

  // Halo per-lane source pointers: slab j = wv+4i (j>22 -> idempotent dup of
  // this wave's previous slab so every wave issues exactly 6 loads).
  const u16* hptr[6]; int hslab[6];
  #pragma unroll
  for (int i = 0; i < 6; i++) {
    int j = wv + 4*i;
    if (j > 22) j -= 4;                        // wv3,i=5 -> slab 19 (dup)
    hslab[i] = j;
    const int item = j*64 + ln;
    int hp = item >> 3; if (hp >= 180) hp -= 180;
    const int g = item & 7;
    const int hy = hp / 18, hx = hp - hy*18;
    const int prow = c_poff[lv] + (ty0 + hy)*wrow2 + tx0 + hx;
    hptr[i] = X + (size_t)prow*64 + ((g ^ (hp & 7)) << 3);
  }

  auto stageH = [&](int plane) {               // 6 loads/wave
    u16* dst = &hB[(plane & 1) * HSTR];
    const size_t cof = (size_t)plane * PLS;
    #pragma unroll
    for (int i = 0; i < 6; i++)
      g2l16(hptr[i] + cof, dst + hslab[i]*512, ln);
  };
  auto stageA = [&](int s, int b) {            // 4 loads/wave
    const u16* as = abase + (size_t)s * ASTR;
    u16* da = &sA[wv][b][0];
    #pragma unroll
    for (int j = 0; j < 4; j++) g2l16(as + j*512, da + j*512, ln);
  };

  f32x4 acc[2][8];
  #pragma unroll
  for (int i = 0; i < 2; i++)
    #pragma unroll
    for (int j = 0; j < 8; j++) acc[i][j] = (f32x4){0.f, 0.f, 0.f, 0.f};

  // fragment sets: sub0 (af0/bf0) is the cross-iteration prefetch target;
  // sub1 (af1/bf1) is read within the iteration. Peak live = 80 VGPR (same
  // as the unpipelined version: prefetch reuses the just-consumed sub0 set).
  bf16x8 af0[2], bf0[8], af1[2], bf1[8];

  auto rdA = [&](const u16* myA, int q, bf16x8 (&af)[2]) {
    const int swzA = (q ^ (l15 & 7)) * 8;
    #pragma unroll
    for (int mt = 0; mt < 2; mt++)
      af[mt] = *(const bf16x8*)&myA[(mt*16 + l15)*64 + swzA];
  };
  auto rdB = [&](const u16* hpl, int q, int tapv, bf16x8 (&bf)[8]) {
    const int dh = tapv / 3, dw = tapv - dh*3;
    #pragma unroll
    for (int nt = 0; nt < 8; nt++) {
      const int hp = (nt + dh)*18 + l15 + dw;
      bf[nt] = *(const bf16x8*)&hpl[hp*64 + ((q ^ (hp & 7)) << 3)];
    }
  };
  auto mm = [&](const bf16x8 (&af)[2], const bf16x8 (&bf)[8]) {
    __builtin_amdgcn_s_setprio(1);
    #pragma unroll
    for (int mt = 0; mt < 2; mt++)
      #pragma unroll
      for (int nt = 0; nt < 8; nt++)
        acc[mt][nt] = __builtin_amdgcn_mfma_f32_16x16x32_bf16(
            af[mt], bf[nt], acc[mt][nt], 0, 0, 0);
    __builtin_amdgcn_s_setprio(0);
  };
  auto stageAfor = [&](int t_, int tap_, int cc_) {  // stage A for t_+2
    int tap2 = tap_ + 2, cc2 = cc_;
    if (tap2 >= 9) { tap2 -= 9; cc2++; }
    stageA(tap2*4 + cc2, t_ & 1);
  };
  auto pre = [&](int t_, int tap_, int cc_) {        // sub0 frags for t_+1
    int tapn = tap_ + 1, ccn = cc_;
    if (tapn >= 9) { tapn = 0; ccn++; }
    rdA(&sA[wv][(t_ + 1) & 1][0], quad, af0);
    rdB(&hB[(ccn & 1) * HSTR], quad, tapn, bf0);
  };

  if (MODE == 0 && tid < 32) sstat[tid >> 1][tid & 1] = 0.f;

  // ---- prologue: halo planes 0,1 + A stages for t=0,1; one barrier ----
  stageH(0);
  stageH(1);
  stageA(0, 0);                                // t=0: tap0 cc0 -> s=0
  stageA(4, 1);                                // t=1: tap1 cc0 -> s=4
  __syncthreads();                             // drains vm; LDS visible
  rdA(&sA[wv][0][0], quad, af0);               // prefetch sub0(0)
  rdB(&hB[0], quad, 0, bf0);

  // ---- K-loop: t = cc*9 + tap ----
  int cc = 0, tap = 0;
  #pragma unroll 1
  for (int t = 0; t < 36; t++) {
    const u16* myA = &sA[wv][t & 1][0];
    const u16* hpl = &hB[(cc & 1) * HSTR];
    if (tap == 0 && cc > 0) {                  // t = 9,18,27
      __builtin_amdgcn_sched_barrier(0);
      __builtin_amdgcn_s_barrier();            // all waves done w/ old plane
      __builtin_amdgcn_sched_barrier(0);
    }
    if (t == 18 || t == 27) {
      // fresh restart: prefetch was skipped at t-1 (halo plane only proven
      // complete by THIS barrier). Old-style full read.
      __builtin_amdgcn_s_waitcnt(WAIT_VM4);    // queue A(t),A(t+1) -> A(t) in
      rdA(myA, quad, af0);       rdB(hpl, quad,     tap, bf0);
      rdA(myA, 4 + quad, af1);   rdB(hpl, 4 + quad, tap, bf1);
      __builtin_amdgcn_s_waitcnt(WAIT_LGKM10); // sub0 ready, sub1 flying
      mm(af0, bf0);
      __builtin_amdgcn_s_waitcnt(WAIT_LGKM0);  // sub1 ready; bufs reusable
      stageAfor(t, tap, cc);                   // A(t+2)
      if (t == 18) stageH(3);                  // t=27: no more planes
      if (t == 18) __builtin_amdgcn_s_waitcnt(WAIT_VM10); // A19|A20,H3 fly
      else         __builtin_amdgcn_s_waitcnt(WAIT_VM4);  // A28|A29 fly
      pre(t, tap, cc);                         // sub0(t+1)
      __builtin_amdgcn_sched_barrier(0);       // pin reads before MFMAs
      mm(af1, bf1);
    } else {
      rdA(myA, 4 + quad, af1);                 // issue sub1(t) reads first
      rdB(hpl, 4 + quad, tap, bf1);
      __builtin_amdgcn_s_waitcnt(WAIT_LGKM10); // sub0(t) (prefetched) ready
      mm(af0, bf0);
      __builtin_amdgcn_s_waitcnt(WAIT_LGKM0);  // sub1 ready; bufs reusable
      if (t < 34) stageAfor(t, tap, cc);       // A(t+2)
      if (t == 9) stageH(2);                   // after stageA: A-chain waits
      if (t < 35 && t != 17 && t != 26) {      // prefetch sub0(t+1)
        // prove A(t+1) landed (in-order): allowed = newer-than-A(t+1) ops
        if (t == 9 || t == 10 || t == 19)
             __builtin_amdgcn_s_waitcnt(WAIT_VM10);  // halo batch in queue
        else if (t == 34)
             __builtin_amdgcn_s_waitcnt(WAIT_VM0);   // only A(35) left
        else __builtin_amdgcn_s_waitcnt(WAIT_VM4);
        pre(t, tap, cc);
      }
      __builtin_amdgcn_sched_barrier(0);       // pin reads before MFMAs
      mm(af1, bf1);
    }
    if (++tap == 9) { tap = 0; cc++; }
  }

  const int gx = tx0 + l15;
  if (MODE == 0) {
    const float* __restrict__ bias = br ? bb : bc;
    float* __restrict__ Y = br ? Yb : Yc;
    #pragma unroll
    for (int mt = 0; mt < 2; mt++) {
      const int mloc = wv*32 + mt*16 + quad*4;
      const int mrow = mtile*128 + mloc;
      const f32x4 bv = *(const f32x4*)&bias[mrow];
      float s = 0.f, sq = 0.f;
      #pragma unroll
      for (int nt = 0; nt < 8; nt++) {
        const int gy = ty0 + nt;
        f32x4 v = acc[mt][nt] + bv;
        if (gy < W && gx < W) {
          const size_t n = (size_t)(c_off[lv] + gy*W + gx);
          *(f32x4*)&Y[n*CCH + mrow] = v;
          #pragma unroll
          for (int r = 0; r < 4; r++) { s += v[r]; sq += v[r]*v[r]; }
        }
      }
      #pragma unroll
      for (int o = 1; o < 16; o <<= 1) { s += __shfl_xor(s, o); sq += __shfl_xor(sq, o); }
      if (l15 == 0) {
        const int g = mloc >> 3;               // local 8-ch GN group 0..15
        atomicAdd(&sstat[g][0], s);
        atomicAdd(&sstat[g][1], sq);
      }
    }
    __syncthreads();
    if (tid < 32) {
      const int g = tid >> 1, c = tid & 1;
      atomicAdd(&stats[((br*NLEV + lv)*32 + mtile*16 + g)*2 + c], sstat[g][c]);
    }
  } else {
    const float scl = scales[lv];
    const float stf = c_stridef[lv];
    #pragma unroll
    for (int mt = 0; mt < 2; mt++) {
      const int mr0 = wv*32 + mt*16 + quad*4;
      if (mr0 >= 85) continue;
      #pragma unroll
      for (int nt = 0; nt < 8; nt++) {
        const int gy = ty0 + nt;
        if (gy >= W || gx >= W) continue;
        const size_t n = (size_t)(c_off[lv] + gy*W + gx);
        const f32x4 v = acc[mt][nt];
        #pragma unroll
        for (int r = 0; r < 4; r++) {
          const int m = mr0 + r;
          if (br == 0) {
            if (m < 80) out[n*85 + m] = v[r] + bc[m];          // logits
          } else {
            if (m < 4) {
              const float t = (v[r] + predb[m]) * scl;         // Scale module
              out[n*85 + 80 + m] = fmaxf(t, 0.f) * stf;        // relu * stride
            } else if (m == 4) {
              out[n*85 + 84] = v[r] + ioub[0];                 // iou
            }
          }
        }
      }
    }
  }
}

// GN finalize + affine + ReLU + bf16 cast into PLANAR padded layout.
// Y already includes conv bias.
__global__ __launch_bounds__(256) void gn_relu(
    const float* __restrict__ Yc, const float* __restrict__ Yb,
    const float* __restrict__ stats,
    const float* __restrict__ gwc, const float* __restrict__ gbc,
    const float* __restrict__ gwb, const float* __restrict__ gbb,
    u16* __restrict__ Xc, u16* __restrict__ Xb)
{
  const int t = blockIdx.x * 256 + threadIdx.x;
  if (t >= 2 * P_TOT * 32) return;
  const int br = t / (P_TOT * 32);
  const int r  = t - br * (P_TOT * 32);
  const int pg = r >> 5;
  const int c0 = (r & 31) << 3;
  int lv = 0;
  #pragma unroll
  for (int i = 1; i < NLEV; i++) if (pg >= c_off[i]) lv = i;
  const int pl = pg - c_off[lv];
  const int Wl = c_W[lv];
  const int g = c0 >> 3;
  const float* st = &stats[(((size_t)br*NLEV + lv)*32 + g)*2];
  const float cnt = 8.f * (float)c_HW[lv];
  const float mean = st[0] / cnt;
  const float var  = st[1] / cnt - mean*mean;
  const float rstd = rsqrtf(var + 1e-5f);
  const float* Y  = br ? Yb : Yc;
  const float* gw = br ? gwb : gwc;
  const float* gb = br ? gbb : gbc;
  u16* X = br ? Xb : Xc;
  const float* y = &Y[(size_t)pg*CCH + c0];
  const int h = pl / Wl, wi = pl - h*Wl;
  const size_t pidx = (size_t)(c_poff[lv] + (h+1)*(Wl+2) + (wi+1));
  union { u16 u[8]; uint4 v; } pk;
  #pragma unroll
  for (int i = 0; i < 8; i++) {
    const float v = (y[i] - mean)*rstd*gw[c0+i] + gb[c0+i];
    pk.u[i] = f2bf(fmaxf(v, 0.f));
  }
  *(uint4*)&X[(size_t)(c0 >> 6)*PLS + pidx*64 + (c0 & 63)] = pk.v;
}

// fp32 NCHW feats -> bf16 planar padded
__global__ __launch_bounds__(256) void feat2bf(
    const float* __restrict__ p3, const float* __restrict__ p4,
    const float* __restrict__ p5, const float* __restrict__ p6,
    const float* __restrict__ p7, u16* __restrict__ X)
{
  const int t = blockIdx.x * 256 + threadIdx.x;
  if (t >= P_TOT * 32) return;
  const int pg = t >> 5, c0 = (t & 31) << 3;
  int lv = 0;
  #pragma unroll
  for (int i = 1; i < NLEV; i++) if (pg >= c_off[i]) lv = i;
  const int pl = pg - c_off[lv];
  const float* src = lv==0 ? p3 : lv==1 ? p4 : lv==2 ? p5 : lv==3 ? p6 : p7;
  const int HW = c_HW[lv], Wl = c_W[lv];
  const int h = pl / Wl, wi = pl - h*Wl;
  const size_t pidx = (size_t)(c_poff[lv] + (h+1)*(Wl+2) + (wi+1));
  union { u16 u[8]; uint4 v; } pk;
  #pragma unroll
  for (int i = 0; i < 8; i++)
    pk.u[i] = f2bf(src[(size_t)(c0+i)*HW + pl]);
  *(uint4*)&X[(size_t)(c0 >> 6)*PLS + pidx*64 + (c0 & 63)] = pk.v;
}

// tower weights [l][co][ci][9] fp32 -> PACKED stage-major swizzled bf16:
// dst = l*589824 + ((s*32 + (co>>3))*64 + (co&7)*8 + ((kl>>3)^(co&7)))*8 + (kl&7)
// where k = tap*256+ci, s = k>>6 = tap*4 + (ci>>6), kl = k&63.
__global__ __launch_bounds__(256) void wconv(
    const float* __restrict__ cw, const float* __restrict__ bw,
    u16* __restrict__ Wc, u16* __restrict__ Wb)
{
  const size_t N = (size_t)4*256*KTOT;
  const size_t t = (size_t)blockIdx.x * 256 + threadIdx.x;
  if (t >= 2*N) return;
  const float* src = (t < N) ? cw : bw;
  u16* dst = (t < N) ? Wc : Wb;
  const size_t i = (t < N) ? t : t - N;
  const size_t lc = i / KTOT;
  const int kk = (int)(i - lc*KTOT);
  const int l = (int)(lc >> 8), co = (int)(lc & 255);
  const int tap = kk >> 8, ci = kk & 255;
  const int s = kk >> 6, kl = kk & 63;
  const int r = co & 7, p = (kl >> 3) ^ r;
  const size_t d = (size_t)l*589824 +
      ((size_t)((s*32 + (co >> 3))*64 + r*8 + p))*8 + (kl & 7);
  dst[d] = f2bf(src[(lc*256 + ci)*9 + tap]);
}

// head weights -> packed 128-row swizzled (cls: 80 rows; box: 4 pred + 1 iou)
__global__ __launch_bounds__(256) void hconv(
    const float* __restrict__ sw, const float* __restrict__ pw,
    const float* __restrict__ iw, u16* __restrict__ Whc, u16* __restrict__ Whb)
{
  const int N = 128 * KTOT;
  const int t = blockIdx.x * 256 + threadIdx.x;
  if (t >= 2*N) return;
  const int i = (t < N) ? t : t - N;
  const int co = i / KTOT, kk = i - co*KTOT;
  const int tap = kk >> 8, ci = kk & 255;
  const int s = kk >> 6, kl = kk & 63;
  const int r = co & 7, p = (kl >> 3) ^ r;
  const size_t d = ((size_t)((s*16 + (co >> 3))*64 + r*8 + p))*8 + (kl & 7);
  float v = 0.f;
  if (t < N) {
    if (co < 80) v = sw[(co*256 + ci)*9 + tap];
    Whc[d] = f2bf(v);
  } else {
    if (co < 4)       v = pw[(co*256 + ci)*9 + tap];
    else if (co == 4) v = iw[ci*9 + tap];
    Whb[d] = f2bf(v);
  }
}

extern "C" void kernel_launch(void* const* d_in, const int* in_sizes, int n_in,
                              void* d_out, int out_size, void* d_ws, size_t ws_size,
                              hipStream_t stream)
{
  const float* p3      = (const float*)d_in[0];
  const float* p4      = (const float*)d_in[1];
  const float* p5      = (const float*)d_in[2];
  const float* p6      = (const float*)d_in[3];
  const float* p7      = (const float*)d_in[4];
  const float* cls_w   = (const float*)d_in[5];
  const float* cls_b   = (const float*)d_in[6];
  const float* cls_gw  = (const float*)d_in[7];
  const float* cls_gb  = (const float*)d_in[8];
  const float* box_w   = (const float*)d_in[9];
  const float* box_b   = (const float*)d_in[10];
  const float* box_gw  = (const float*)d_in[11];
  const float* box_gb  = (const float*)d_in[12];
  const float* score_w = (const float*)d_in[13];
  const float* score_b = (const float*)d_in[14];
  const float* pred_w  = (const float*)d_in[15];
  const float* pred_b  = (const float*)d_in[16];
  const float* iou_w   = (const float*)d_in[17];
  const float* iou_b   = (const float*)d_in[18];
  const float* scales  = (const float*)d_in[19];
  float* out = (float*)d_out;

  char* w = (char*)d_ws;
  size_t o = 0;
  auto alloc = [&](size_t b) { void* p = w + o; o += (b + 255) & ~(size_t)255; return p; };
  // X buffers + stats first: zeroed by ONE memset (all 256B multiples)
  u16*   XF = (u16*)alloc((size_t)PP_TOT*CCH*2);   // planar [4][PP_TOT][64]
  u16*   XC = (u16*)alloc((size_t)PP_TOT*CCH*2);
  u16*   XB = (u16*)alloc((size_t)PP_TOT*CCH*2);
  float* ST = (float*)alloc((size_t)4*2*NLEV*32*2*4);   // [layer][br][lv][32][2]
  u16*  WRC = (u16*)alloc((size_t)4*256*KTOT*2);
  u16*  WRB = (u16*)alloc((size_t)4*256*KTOT*2);
  u16*  WHC = (u16*)alloc((size_t)128*KTOT*2);
  u16*  WHB = (u16*)alloc((size_t)128*KTOT*2);
  float* YC = (float*)alloc((size_t)P_TOT*CCH*4);
  float* YB = (float*)alloc((size_t)P_TOT*CCH*4);

  // zero padded activation borders + all layers' GN stats in one shot
  hipMemsetAsync(XF, 0, (size_t)3*PP_TOT*CCH*2 + (size_t)4*2*NLEV*32*2*4, stream);

  wconv<<<dim3((unsigned)(((size_t)2*4*256*KTOT + 255)/256)), 256, 0, stream>>>(cls_w, box_w, WRC, WRB);
  hconv<<<dim3((2*128*KTOT + 255)/256), 256, 0, stream>>>(score_w, pred_w, iou_w, WHC, WHB);
  feat2bf<<<dim3((P_TOT*32 + 255)/256), 256, 0, stream>>>(p3, p4, p5, p6, p7, XF);

  const u16* xci = XF; const u16* xbi = XF;
  for (int l = 0; l < 4; l++) {
    float* STl = ST + (size_t)l*2*NLEV*32*2;
    gemm_conv<0><<<dim3(74, 2, 2), 256, 0, stream>>>(
        xci, xbi, WRC + (size_t)l*589824, WRB + (size_t)l*589824,
        cls_b + l*256, box_b + l*256, YC, YB, STl,
        nullptr, nullptr, nullptr, nullptr);
    gn_relu<<<dim3((2*P_TOT*32 + 255)/256), 256, 0, stream>>>(
        YC, YB, STl, cls_gw + l*256, cls_gb + l*256, box_gw + l*256, box_gb + l*256,
        XC, XB);
    xci = XC; xbi = XB;
  }
  gemm_conv<1><<<dim3(74, 1, 2), 256, 0, stream>>>(
      xci, xbi, WHC, WHB, score_b, nullptr, nullptr, nullptr, nullptr,
      pred_b, iou_b, scales, out);
}

// Round 2
// 328.961 us; speedup vs baseline: 1.2969x; 1.2969x over previous
//
#include <hip/hip_runtime.h>

typedef unsigned short u16;
typedef __attribute__((ext_vector_type(8))) short bf16x8;   // 8 x bf16 (4 VGPRs)
typedef __attribute__((ext_vector_type(4))) float f32x4;

#define NLEV 5
#define CCH 256
#define KTOT 2304            // 9 taps * 256 ci
#define P_TOT 8525           // sum HW
#define PP_TOT 9165          // sum (H+2)*(W+2)
#define PLS (PP_TOT*64)      // activation plane stride (u16), 4 planes of 64 ci
#define HSTR 11776           // halo LDS plane stride (u16) = 23 slabs * 512

__constant__ int   c_HW[NLEV]     = {6400, 1600, 400, 100, 25};
__constant__ int   c_W[NLEV]      = {80, 40, 20, 10, 5};    // H == W (square)
__constant__ int   c_off[NLEV]    = {0, 6400, 8000, 8400, 8500};
__constant__ int   c_poff[NLEV]   = {0, 6724, 8488, 8972, 9116};
__constant__ int   c_tls[NLEV+1]  = {0, 50, 65, 71, 73, 74};  // 16x8 tile starts
__constant__ int   c_ntx[NLEV]    = {5, 3, 2, 1, 1};          // tiles across
__constant__ float c_stridef[NLEV]= {8.f, 16.f, 32.f, 64.f, 128.f};

__device__ __forceinline__ u16 f2bf(float f){
  union { float f; unsigned u; } v; v.f = f;
  unsigned r = v.u + 0x7fffu + ((v.u >> 16) & 1u);   // RNE
  return (u16)(r >> 16);
}

// async global->LDS: 64 lanes x 16B; HW writes lane i to ldsbase + i*16.
__device__ __forceinline__ void g2l16(const u16* g, u16* l, int lane){
#if defined(__has_builtin)
#if __has_builtin(__builtin_amdgcn_global_load_lds)
  __builtin_amdgcn_global_load_lds(
      (const __attribute__((address_space(1))) unsigned int*)g,
      (__attribute__((address_space(3))) unsigned int*)l, 16, 0, 0);
  return;
#endif
#endif
  *(uint4*)(l + lane*8) = *(const uint4*)g;  // fallback: sync copy
}

// s_waitcnt imm (gfx9: vm[3:0] bits3:0, vm[5:4] bits15:14, exp[6:4], lgkm[11:8])
#define WAIT_VM12  0x0F7C   // vmcnt(12): allow this titer's A batch in flight

// ---------------------------------------------------------------------------
// LDS-traffic-minimized halo implicit-GEMM conv 3x3 (R1 analysis: old kernel
// was LDS-READ-PIPE bound: 4 waves x 20 KB ds_read per K-step ~ 960 cyc/CU,
// MfmaUtil 6%). Two structural changes:
//  1. dh-reuse: B-frag(tap=(dh,dw), row nt) == B-frag(dw, row nt+dh). Loop
//     titers u=(cc,dw) (12 total); read B rows 0..9 ONCE per (cc,dw,sub) and
//     run all 3 dh taps from registers: B ds_reads 36x16 -> 12x20 (2.4x cut).
//  2. A weights global->REGISTER (no LDS at all for A): packed layout makes
//     each (s,sub,mt) fragment one wave-coalesced 1KB global_load_dwordx4.
//     Consume-then-reload (depth ~1 titer ~ HBM latency); compiler inserts
//     counted vmcnt on the reg defs. sA deleted: LDS 80 KB -> 47 KB.
// Barriers only at cc boundaries (3), wrapped in sched_barrier(0) as before;
// no manual lgkm, no setprio - compiler schedules the titer body freely.
// A layout (u16): d = s*SZ + (co>>5)*2048 + (kl>>5)*1024 + ((co>>4)&1)*512
//                   + ((kl>>3)&3)*128 + (co&15)*8 + (kl&7);  s = tap*4 + cc.
// MODE 0: towers, grid (74,2,2), SZ=16384; GN stats fused in epilogue.
// MODE 1: heads,  grid (74,1,2), SZ=8192: br0 score (m<80), br1 pred+iou.
// ---------------------------------------------------------------------------
template<int MODE>
__global__ __launch_bounds__(256, 2) void gemm_conv(
    const u16* __restrict__ Xc, const u16* __restrict__ Xb,
    const u16* __restrict__ Wc, const u16* __restrict__ Wb,
    const float* __restrict__ bc, const float* __restrict__ bb,
    float* __restrict__ Yc, float* __restrict__ Yb,
    float* __restrict__ stats,
    const float* __restrict__ predb, const float* __restrict__ ioub,
    const float* __restrict__ scales, float* __restrict__ out)
{
  __shared__ u16 hB[2*HSTR];        // 47104 B: halo plane dbuf (slot = cc&1)
  __shared__ float sstat[16][2];    // 128 B

  const int ptile = blockIdx.x;
  const int mtile = (MODE == 0) ? blockIdx.y : 0;
  const int br = blockIdx.z;
  int lv = 0;
  #pragma unroll
  for (int i = 1; i < NLEV; i++) if (ptile >= c_tls[i]) lv = i;
  const int tidx = ptile - c_tls[lv];
  const int ntx = c_ntx[lv];
  const int ty0 = (tidx / ntx) * 8, tx0 = (tidx - (tidx / ntx) * ntx) * 16;
  const int W = c_W[lv], wrow2 = W + 2;

  const int tid = threadIdx.x, wv = tid >> 6, ln = tid & 63;
  const int quad = ln >> 4, l15 = ln & 15;

  const u16* __restrict__ X  = br ? Xb : Xc;   // planar activations
  const u16* __restrict__ WA = br ? Wb : Wc;   // packed weights

  const int SZ = (MODE == 0) ? 16384 : 8192;   // per-stage A u16s
  // per-lane A base: wave group g0 = co>>5
  const u16* aln = WA +
      (size_t)((((MODE == 0) ? (mtile*4 + wv) : wv)) * 2048 + quad*128 + l15*8);

  // Halo per-lane source pointers: slab j = wv+4i (j>22 -> idempotent dup of
  // this wave's previous slab so every wave issues exactly 6 loads).
  const u16* hptr[6]; int hslab[6];
  #pragma unroll
  for (int i = 0; i < 6; i++) {
    int j = wv + 4*i;
    if (j > 22) j -= 4;                        // wv3,i=5 -> slab 19 (dup)
    hslab[i] = j;
    const int item = j*64 + ln;
    int hp = item >> 3; if (hp >= 180) hp -= 180;
    const int g = item & 7;
    const int hy = hp / 18, hx = hp - hy*18;
    const int prow = c_poff[lv] + (ty0 + hy)*wrow2 + tx0 + hx;
    hptr[i] = X + (size_t)prow*64 + ((g ^ (hp & 7)) << 3);
  }

  auto stageH = [&](int plane) {               // 6 loads/wave
    u16* dst = &hB[(plane & 1) * HSTR];
    const size_t cof = (size_t)plane * PLS;
    #pragma unroll
    for (int i = 0; i < 6; i++)
      g2l16(hptr[i] + cof, dst + hslab[i]*512, ln);
  };

  f32x4 acc[2][8];
  #pragma unroll
  for (int i = 0; i < 2; i++)
    #pragma unroll
    for (int j = 0; j < 8; j++) acc[i][j] = (f32x4){0.f, 0.f, 0.f, 0.f};

  // A fragments for the CURRENT titer: [dh][sub][mt], 12 x bf16x8 = 48 VGPR.
  bf16x8 af[3][2][2];
  auto loadA = [&](int cc_, int dw_) {         // 12 coalesced 16B loads
    #pragma unroll
    for (int dh = 0; dh < 3; dh++) {
      const u16* p = aln + (size_t)((dh*3 + dw_)*4 + cc_) * SZ;
      #pragma unroll
      for (int sub = 0; sub < 2; sub++)
        #pragma unroll
        for (int mt = 0; mt < 2; mt++)
          af[dh][sub][mt] = *(const bf16x8*)(p + sub*1024 + mt*512);
    }
  };

  if (MODE == 0 && tid < 32) sstat[tid >> 1][tid & 1] = 0.f;

  // ---- prologue: halo planes 0,1 + A for titer 0; one barrier ----
  stageH(0);
  stageH(1);
  loadA(0, 0);
  __syncthreads();                             // drains vm; LDS+regs valid

  // ---- K-loop: 12 titers u = cc*3 + dw; 3 dh taps per titer from regs ----
  int cc = 0, dw = 0;
  #pragma unroll 1
  for (int u = 0; u < 12; u++) {
    if (dw == 0 && cc > 0) {                   // u = 3,6,9
      __builtin_amdgcn_s_waitcnt(WAIT_VM12);   // drain halo; A batch may fly
      __builtin_amdgcn_sched_barrier(0);
      __builtin_amdgcn_s_barrier();            // all waves done w/ old plane
      __builtin_amdgcn_sched_barrier(0);
      if (cc < 3) stageH(cc + 1);              // into slot (cc+1)&1
    }
    const u16* hpl = &hB[(cc & 1) * HSTR];
    #pragma unroll
    for (int sub = 0; sub < 2; sub++) {
      const int q = sub*4 + quad;
      bf16x8 bf[10];
      #pragma unroll
      for (int n2 = 0; n2 < 10; n2++) {        // B rows 0..9 cover all dh
        const int hp = n2*18 + l15 + dw;
        bf[n2] = *(const bf16x8*)&hpl[hp*64 + ((q ^ (hp & 7)) << 3)];
      }
      #pragma unroll
      for (int dh = 0; dh < 3; dh++)
        #pragma unroll
        for (int mt = 0; mt < 2; mt++)
          #pragma unroll
          for (int nt = 0; nt < 8; nt++)
            acc[mt][nt] = __builtin_amdgcn_mfma_f32_16x16x32_bf16(
                af[dh][sub][mt], bf[nt + dh], acc[mt][nt], 0, 0, 0);
    }
    // reload A for next titer (WAR on af keeps these after the consumers)
    int dwn = dw + 1, ccn = cc;
    if (dwn == 3) { dwn = 0; ccn++; }
    if (u < 11) loadA(ccn, dwn);
    dw = dwn; cc = ccn;
  }

  const int gx = tx0 + l15;
  if (MODE == 0) {
    const float* __restrict__ bias = br ? bb : bc;
    float* __restrict__ Y = br ? Yb : Yc;
    #pragma unroll
    for (int mt = 0; mt < 2; mt++) {
      const int mloc = wv*32 + mt*16 + quad*4;
      const int mrow = mtile*128 + mloc;
      const f32x4 bv = *(const f32x4*)&bias[mrow];
      float s = 0.f, sq = 0.f;
      #pragma unroll
      for (int nt = 0; nt < 8; nt++) {
        const int gy = ty0 + nt;
        f32x4 v = acc[mt][nt] + bv;
        if (gy < W && gx < W) {
          const size_t n = (size_t)(c_off[lv] + gy*W + gx);
          *(f32x4*)&Y[n*CCH + mrow] = v;
          #pragma unroll
          for (int r = 0; r < 4; r++) { s += v[r]; sq += v[r]*v[r]; }
        }
      }
      #pragma unroll
      for (int o = 1; o < 16; o <<= 1) { s += __shfl_xor(s, o); sq += __shfl_xor(sq, o); }
      if (l15 == 0) {
        const int g = mloc >> 3;               // local 8-ch GN group 0..15
        atomicAdd(&sstat[g][0], s);
        atomicAdd(&sstat[g][1], sq);
      }
    }
    __syncthreads();
    if (tid < 32) {
      const int g = tid >> 1, c = tid & 1;
      atomicAdd(&stats[((br*NLEV + lv)*32 + mtile*16 + g)*2 + c], sstat[g][c]);
    }
  } else {
    const float scl = scales[lv];
    const float stf = c_stridef[lv];
    #pragma unroll
    for (int mt = 0; mt < 2; mt++) {
      const int mr0 = wv*32 + mt*16 + quad*4;
      if (mr0 >= 85) continue;
      #pragma unroll
      for (int nt = 0; nt < 8; nt++) {
        const int gy = ty0 + nt;
        if (gy >= W || gx >= W) continue;
        const size_t n = (size_t)(c_off[lv] + gy*W + gx);
        const f32x4 v = acc[mt][nt];
        #pragma unroll
        for (int r = 0; r < 4; r++) {
          const int m = mr0 + r;
          if (br == 0) {
            if (m < 80) out[n*85 + m] = v[r] + bc[m];          // logits
          } else {
            if (m < 4) {
              const float t = (v[r] + predb[m]) * scl;         // Scale module
              out[n*85 + 80 + m] = fmaxf(t, 0.f) * stf;        // relu * stride
            } else if (m == 4) {
              out[n*85 + 84] = v[r] + ioub[0];                 // iou
            }
          }
        }
      }
    }
  }
}

// GN finalize + affine + ReLU + bf16 cast into PLANAR padded layout.
// Y already includes conv bias.
__global__ __launch_bounds__(256) void gn_relu(
    const float* __restrict__ Yc, const float* __restrict__ Yb,
    const float* __restrict__ stats,
    const float* __restrict__ gwc, const float* __restrict__ gbc,
    const float* __restrict__ gwb, const float* __restrict__ gbb,
    u16* __restrict__ Xc, u16* __restrict__ Xb)
{
  const int t = blockIdx.x * 256 + threadIdx.x;
  if (t >= 2 * P_TOT * 32) return;
  const int br = t / (P_TOT * 32);
  const int r  = t - br * (P_TOT * 32);
  const int pg = r >> 5;
  const int c0 = (r & 31) << 3;
  int lv = 0;
  #pragma unroll
  for (int i = 1; i < NLEV; i++) if (pg >= c_off[i]) lv = i;
  const int pl = pg - c_off[lv];
  const int Wl = c_W[lv];
  const int g = c0 >> 3;
  const float* st = &stats[(((size_t)br*NLEV + lv)*32 + g)*2];
  const float cnt = 8.f * (float)c_HW[lv];
  const float mean = st[0] / cnt;
  const float var  = st[1] / cnt - mean*mean;
  const float rstd = rsqrtf(var + 1e-5f);
  const float* Y  = br ? Yb : Yc;
  const float* gw = br ? gwb : gwc;
  const float* gb = br ? gbb : gbc;
  u16* X = br ? Xb : Xc;
  const float* y = &Y[(size_t)pg*CCH + c0];
  const int h = pl / Wl, wi = pl - h*Wl;
  const size_t pidx = (size_t)(c_poff[lv] + (h+1)*(Wl+2) + (wi+1));
  union { u16 u[8]; uint4 v; } pk;
  #pragma unroll
  for (int i = 0; i < 8; i++) {
    const float v = (y[i] - mean)*rstd*gw[c0+i] + gb[c0+i];
    pk.u[i] = f2bf(fmaxf(v, 0.f));
  }
  *(uint4*)&X[(size_t)(c0 >> 6)*PLS + pidx*64 + (c0 & 63)] = pk.v;
}

// fp32 NCHW feats -> bf16 planar padded
__global__ __launch_bounds__(256) void feat2bf(
    const float* __restrict__ p3, const float* __restrict__ p4,
    const float* __restrict__ p5, const float* __restrict__ p6,
    const float* __restrict__ p7, u16* __restrict__ X)
{
  const int t = blockIdx.x * 256 + threadIdx.x;
  if (t >= P_TOT * 32) return;
  const int pg = t >> 5, c0 = (t & 31) << 3;
  int lv = 0;
  #pragma unroll
  for (int i = 1; i < NLEV; i++) if (pg >= c_off[i]) lv = i;
  const int pl = pg - c_off[lv];
  const float* src = lv==0 ? p3 : lv==1 ? p4 : lv==2 ? p5 : lv==3 ? p6 : p7;
  const int HW = c_HW[lv], Wl = c_W[lv];
  const int h = pl / Wl, wi = pl - h*Wl;
  const size_t pidx = (size_t)(c_poff[lv] + (h+1)*(Wl+2) + (wi+1));
  union { u16 u[8]; uint4 v; } pk;
  #pragma unroll
  for (int i = 0; i < 8; i++)
    pk.u[i] = f2bf(src[(size_t)(c0+i)*HW + pl]);
  *(uint4*)&X[(size_t)(c0 >> 6)*PLS + pidx*64 + (c0 & 63)] = pk.v;
}

// tower weights [l][co][ci][9] fp32 -> A-register packed bf16 layout:
// d = l*589824 + s*16384 + (co>>5)*2048 + (kl>>5)*1024 + ((co>>4)&1)*512
//     + ((kl>>3)&3)*128 + (co&15)*8 + (kl&7);  k = tap*256+ci, s=k>>6, kl=k&63.
__global__ __launch_bounds__(256) void wconv(
    const float* __restrict__ cw, const float* __restrict__ bw,
    u16* __restrict__ Wc, u16* __restrict__ Wb)
{
  const size_t N = (size_t)4*256*KTOT;
  const size_t t = (size_t)blockIdx.x * 256 + threadIdx.x;
  if (t >= 2*N) return;
  const float* src = (t < N) ? cw : bw;
  u16* dst = (t < N) ? Wc : Wb;
  const size_t i = (t < N) ? t : t - N;
  const size_t lc = i / KTOT;
  const int kk = (int)(i - lc*KTOT);
  const int l = (int)(lc >> 8), co = (int)(lc & 255);
  const int tap = kk >> 8, ci = kk & 255;
  const int s = kk >> 6, kl = kk & 63;
  const size_t d = (size_t)l*589824 + (size_t)s*16384 +
      (size_t)((co >> 5)*2048 + (kl >> 5)*1024 + ((co >> 4) & 1)*512 +
               ((kl >> 3) & 3)*128 + (co & 15)*8 + (kl & 7));
  dst[d] = f2bf(src[(lc*256 + ci)*9 + tap]);
}

// head weights -> A-register packed (cls: 80 rows; box: 4 pred + 1 iou),
// 128 co rows, per-stage size 8192 u16.
__global__ __launch_bounds__(256) void hconv(
    const float* __restrict__ sw, const float* __restrict__ pw,
    const float* __restrict__ iw, u16* __restrict__ Whc, u16* __restrict__ Whb)
{
  const int N = 128 * KTOT;
  const int t = blockIdx.x * 256 + threadIdx.x;
  if (t >= 2*N) return;
  const int i = (t < N) ? t : t - N;
  const int co = i / KTOT, kk = i - co*KTOT;
  const int tap = kk >> 8, ci = kk & 255;
  const int s = kk >> 6, kl = kk & 63;
  const size_t d = (size_t)s*8192 +
      (size_t)((co >> 5)*2048 + (kl >> 5)*1024 + ((co >> 4) & 1)*512 +
               ((kl >> 3) & 3)*128 + (co & 15)*8 + (kl & 7));
  float v = 0.f;
  if (t < N) {
    if (co < 80) v = sw[(co*256 + ci)*9 + tap];
    Whc[d] = f2bf(v);
  } else {
    if (co < 4)       v = pw[(co*256 + ci)*9 + tap];
    else if (co == 4) v = iw[ci*9 + tap];
    Whb[d] = f2bf(v);
  }
}

extern "C" void kernel_launch(void* const* d_in, const int* in_sizes, int n_in,
                              void* d_out, int out_size, void* d_ws, size_t ws_size,
                              hipStream_t stream)
{
  const float* p3      = (const float*)d_in[0];
  const float* p4      = (const float*)d_in[1];
  const float* p5      = (const float*)d_in[2];
  const float* p6      = (const float*)d_in[3];
  const float* p7      = (const float*)d_in[4];
  const float* cls_w   = (const float*)d_in[5];
  const float* cls_b   = (const float*)d_in[6];
  const float* cls_gw  = (const float*)d_in[7];
  const float* cls_gb  = (const float*)d_in[8];
  const float* box_w   = (const float*)d_in[9];
  const float* box_b   = (const float*)d_in[10];
  const float* box_gw  = (const float*)d_in[11];
  const float* box_gb  = (const float*)d_in[12];
  const float* score_w = (const float*)d_in[13];
  const float* score_b = (const float*)d_in[14];
  const float* pred_w  = (const float*)d_in[15];
  const float* pred_b  = (const float*)d_in[16];
  const float* iou_w   = (const float*)d_in[17];
  const float* iou_b   = (const float*)d_in[18];
  const float* scales  = (const float*)d_in[19];
  float* out = (float*)d_out;

  char* w = (char*)d_ws;
  size_t o = 0;
  auto alloc = [&](size_t b) { void* p = w + o; o += (b + 255) & ~(size_t)255; return p; };
  // X buffers + stats first: zeroed by ONE memset (all 256B multiples)
  u16*   XF = (u16*)alloc((size_t)PP_TOT*CCH*2);   // planar [4][PP_TOT][64]
  u16*   XC = (u16*)alloc((size_t)PP_TOT*CCH*2);
  u16*   XB = (u16*)alloc((size_t)PP_TOT*CCH*2);
  float* ST = (float*)alloc((size_t)4*2*NLEV*32*2*4);   // [layer][br][lv][32][2]
  u16*  WRC = (u16*)alloc((size_t)4*256*KTOT*2);
  u16*  WRB = (u16*)alloc((size_t)4*256*KTOT*2);
  u16*  WHC = (u16*)alloc((size_t)128*KTOT*2);
  u16*  WHB = (u16*)alloc((size_t)128*KTOT*2);
  float* YC = (float*)alloc((size_t)P_TOT*CCH*4);
  float* YB = (float*)alloc((size_t)P_TOT*CCH*4);

  // zero padded activation borders + all layers' GN stats in one shot
  hipMemsetAsync(XF, 0, (size_t)3*PP_TOT*CCH*2 + (size_t)4*2*NLEV*32*2*4, stream);

  wconv<<<dim3((unsigned)(((size_t)2*4*256*KTOT + 255)/256)), 256, 0, stream>>>(cls_w, box_w, WRC, WRB);
  hconv<<<dim3((2*128*KTOT + 255)/256), 256, 0, stream>>>(score_w, pred_w, iou_w, WHC, WHB);
  feat2bf<<<dim3((P_TOT*32 + 255)/256), 256, 0, stream>>>(p3, p4, p5, p6, p7, XF);

  const u16* xci = XF; const u16* xbi = XF;
  for (int l = 0; l < 4; l++) {
    float* STl = ST + (size_t)l*2*NLEV*32*2;
    gemm_conv<0><<<dim3(74, 2, 2), 256, 0, stream>>>(
        xci, xbi, WRC + (size_t)l*589824, WRB + (size_t)l*589824,
        cls_b + l*256, box_b + l*256, YC, YB, STl,
        nullptr, nullptr, nullptr, nullptr);
    gn_relu<<<dim3((2*P_TOT*32 + 255)/256), 256, 0, stream>>>(
        YC, YB, STl, cls_gw + l*256, cls_gb + l*256, box_gw + l*256, box_gb + l*256,
        XC, XB);
    xci = XC; xbi = XB;
  }
  gemm_conv<1><<<dim3(74, 1, 2), 256, 0, stream>>>(
      xci, xbi, WHC, WHB, score_b, nullptr, nullptr, nullptr, nullptr,
      pred_b, iou_b, scales, out);
}